// Round 1
// baseline (350.774 us; speedup 1.0000x reference)
//
#include <hip/hip_runtime.h>
#include <hip/hip_bf16.h>

#define DEPTH 25
#define DIM   64
#define HID   100

typedef _Float16 f16x4 __attribute__((ext_vector_type(4)));
typedef float    f32x4 __attribute__((ext_vector_type(4)));

// One block = 256 threads = 4 waves. Each wave owns 16 batch rows.
// State is kept TRANSPOSED: out^T [64 feat x 16 rows]. Each step computes
// E = W_drift^T @ out^T via v_mfma_f32_16x16x16f16; the MFMA C/D layout
// (row=(lane>>4)*4+reg, col=lane&15) equals the B-operand layout
// (k=(lane>>4)*4+i, n=lane&15), so the fp32 master state maps directly to
// the next step's B fragments with only an in-lane f32->f16 convert.
__global__ __launch_bounds__(256) void sdenet_fused(
    const float* __restrict__ x,      const float* __restrict__ u_raw,
    const float* __restrict__ w_raw,  const float* __restrict__ W_down,
    const float* __restrict__ b_down, const float* __restrict__ W_drift,
    const float* __restrict__ b_drift,const float* __restrict__ W1,
    const float* __restrict__ b1,     const float* __restrict__ W2,
    const float* __restrict__ b2,     float* __restrict__ out,
    int batch)
{
    __shared__ float noise_lds[DEPTH * DIM];

    const int tid = threadIdx.x;

    // ---- Levy noise (Chambers-Mallows-Stuck, symmetric alpha=1.8) ----
    for (int idx = tid; idx < DEPTH * DIM; idx += 256) {
        float u = u_raw[idx];
        float w = w_raw[idx];
        float U  = 3.14159265358979323846f * (u - 0.5f);
        float Wv = -logf(fminf(fmaxf(w, 1e-12f), 1.0f));
        float t1 = sinf(1.8f * U) / powf(cosf(U), 0.5555555555555556f);
        float ratio = cosf(0.8f * U) / fmaxf(Wv, 1e-12f);
        float X = t1 * powf(ratio, -0.4444444444444444f);
        noise_lds[idx] = fminf(fmaxf(0.1f * X, -10.0f), 10.0f);
    }
    __syncthreads();

    const int wave = tid >> 6;
    const int lane = tid & 63;
    const int r    = lane & 15;        // batch row within wave tile (B-operand col)
    const int g    = lane >> 4;        // 0..3 k/row group
    const int row  = blockIdx.x * 64 + wave * 16 + r;   // global batch row
    const float dt = 0.04f;

    // ---- initial: out0^T = W_down^T @ x^T + b_down ----
    // B fragments from x (x[row][k], k = kt*16 + g*4 + i)
    f16x4 bfrag[4];
    #pragma unroll
    for (int kt = 0; kt < 4; ++kt) {
        const float4 xv = *(const float4*)(x + row * DIM + kt * 16 + g * 4);
        f16x4 t;
        t[0] = (_Float16)xv.x; t[1] = (_Float16)xv.y;
        t[2] = (_Float16)xv.z; t[3] = (_Float16)xv.w;
        bfrag[kt] = t;
    }

    float out_f[4][4];   // master state fp32: out^T[Mt*16+g*4+reg][r]
    #pragma unroll
    for (int Mt = 0; Mt < 4; ++Mt) {
        // C init = b_down fragment (row n = Mt*16 + g*4 + reg)
        f32x4 acc = *(const f32x4*)(b_down + Mt * 16 + g * 4);
        #pragma unroll
        for (int kt = 0; kt < 4; ++kt) {
            // A frag: W_down^T tile(Mt,kt): A[m=r][k=g*4+i] = W_down[kt*16+g*4+i][Mt*16+r]
            f16x4 a;
            #pragma unroll
            for (int i = 0; i < 4; ++i)
                a[i] = (_Float16)W_down[(kt * 16 + g * 4 + i) * DIM + Mt * 16 + r];
            acc = __builtin_amdgcn_mfma_f32_16x16x16f16(a, bfrag[kt], acc, 0, 0, 0);
        }
        #pragma unroll
        for (int reg = 0; reg < 4; ++reg) out_f[Mt][reg] = acc[reg];
    }

    // refresh B fragments from out0 (used by head and first loop step)
    #pragma unroll
    for (int kt = 0; kt < 4; ++kt) {
        f16x4 t;
        #pragma unroll
        for (int i = 0; i < 4; ++i) t[i] = (_Float16)out_f[kt][i];
        bfrag[kt] = t;
    }

    // ---- head: logit = relu(out0 @ W1 + b1) @ W2 + b2  (on initial state) ----
    float partial = 0.0f;
    #pragma unroll
    for (int Mt = 0; Mt < 7; ++Mt) {          // hid padded 100 -> 112
        f32x4 acc;
        #pragma unroll
        for (int reg = 0; reg < 4; ++reg) {
            int n = Mt * 16 + g * 4 + reg;
            acc[reg] = (n < HID) ? b1[n] : 0.0f;
        }
        const int ncol = Mt * 16 + r;          // W1 output index for A row
        #pragma unroll
        for (int kt = 0; kt < 4; ++kt) {
            f16x4 a;
            #pragma unroll
            for (int i = 0; i < 4; ++i) {
                int k = kt * 16 + g * 4 + i;
                float v = (ncol < HID) ? W1[k * HID + ncol] : 0.0f;
                a[i] = (_Float16)v;
            }
            acc = __builtin_amdgcn_mfma_f32_16x16x16f16(a, bfrag[kt], acc, 0, 0, 0);
        }
        #pragma unroll
        for (int reg = 0; reg < 4; ++reg) {
            int n = Mt * 16 + g * 4 + reg;
            if (n < HID) partial += fmaxf(acc[reg], 0.0f) * W2[n];
        }
    }
    // reduce over g (lanes r, r+16, r+32, r+48)
    partial += __shfl_xor(partial, 16);
    partial += __shfl_xor(partial, 32);
    const float logit = partial + b2[0];
    const float scale = 0.5f * (1.0f / (1.0f + expf(-logit)))
                      * powf(0.04f, 1.0f / 1.8f);

    // ---- persistent W_drift^T A-fragments + b_drift fragment ----
    f16x4 aWd[4][4];
    #pragma unroll
    for (int Mt = 0; Mt < 4; ++Mt)
        #pragma unroll
        for (int kt = 0; kt < 4; ++kt) {
            f16x4 a;
            #pragma unroll
            for (int i = 0; i < 4; ++i)
                a[i] = (_Float16)W_drift[(kt * 16 + g * 4 + i) * DIM + Mt * 16 + r];
            aWd[Mt][kt] = a;
        }
    f32x4 biasd[4];
    #pragma unroll
    for (int Mt = 0; Mt < 4; ++Mt)
        biasd[Mt] = *(const f32x4*)(b_drift + Mt * 16 + g * 4);

    // ---- 25 SDE steps, all in registers ----
    for (int t = 0; t < DEPTH; ++t) {
        f32x4 acc[4];
        #pragma unroll
        for (int Mt = 0; Mt < 4; ++Mt) {
            acc[Mt] = biasd[Mt];
            #pragma unroll
            for (int kt = 0; kt < 4; ++kt)
                acc[Mt] = __builtin_amdgcn_mfma_f32_16x16x16f16(aWd[Mt][kt], bfrag[kt], acc[Mt], 0, 0, 0);
        }
        #pragma unroll
        for (int Mt = 0; Mt < 4; ++Mt) {
            const f32x4 nz = *(const f32x4*)(noise_lds + t * DIM + Mt * 16 + g * 4);
            #pragma unroll
            for (int reg = 0; reg < 4; ++reg) {
                float relu = fmaxf(acc[Mt][reg], 0.0f);
                // out_new = out*(1+dt) + relu*dt + scale*noise
                out_f[Mt][reg] = fmaf(out_f[Mt][reg], 1.04f,
                                      fmaf(relu, dt, scale * nz[reg]));
            }
        }
        #pragma unroll
        for (int kt = 0; kt < 4; ++kt) {
            f16x4 tt;
            #pragma unroll
            for (int i = 0; i < 4; ++i) tt[i] = (_Float16)out_f[kt][i];
            bfrag[kt] = tt;
        }
    }

    // ---- final drift + stores ----
    const long long out2_off = (long long)batch * DIM;
    #pragma unroll
    for (int Mt = 0; Mt < 4; ++Mt) {
        f32x4 acc = biasd[Mt];
        #pragma unroll
        for (int kt = 0; kt < 4; ++kt)
            acc = __builtin_amdgcn_mfma_f32_16x16x16f16(aWd[Mt][kt], bfrag[kt], acc, 0, 0, 0);
        float4 dv, ov;
        dv.x = fmaxf(acc[0], 0.0f) + out_f[Mt][0];
        dv.y = fmaxf(acc[1], 0.0f) + out_f[Mt][1];
        dv.z = fmaxf(acc[2], 0.0f) + out_f[Mt][2];
        dv.w = fmaxf(acc[3], 0.0f) + out_f[Mt][3];
        ov.x = out_f[Mt][0]; ov.y = out_f[Mt][1];
        ov.z = out_f[Mt][2]; ov.w = out_f[Mt][3];
        *(float4*)(out + (long long)row * DIM + Mt * 16 + g * 4) = dv;
        *(float4*)(out + out2_off + (long long)row * DIM + Mt * 16 + g * 4) = ov;
    }
}

extern "C" void kernel_launch(void* const* d_in, const int* in_sizes, int n_in,
                              void* d_out, int out_size, void* d_ws, size_t ws_size,
                              hipStream_t stream) {
    const float* x       = (const float*)d_in[0];
    const float* u_raw   = (const float*)d_in[1];
    const float* w_raw   = (const float*)d_in[2];
    const float* W_down  = (const float*)d_in[3];
    const float* b_down  = (const float*)d_in[4];
    const float* W_drift = (const float*)d_in[5];
    const float* b_drift = (const float*)d_in[6];
    const float* W1      = (const float*)d_in[7];
    const float* b1      = (const float*)d_in[8];
    const float* W2      = (const float*)d_in[9];
    const float* b2      = (const float*)d_in[10];
    float* out = (float*)d_out;

    const int batch = in_sizes[0] / DIM;     // 262144
    const int blocks = batch / 64;           // 64 rows per block (4 waves x 16)

    sdenet_fused<<<blocks, 256, 0, stream>>>(
        x, u_raw, w_raw, W_down, b_down, W_drift, b_drift,
        W1, b1, W2, b2, out, batch);
}

// Round 2
// 280.047 us; speedup vs baseline: 1.2526x; 1.2526x over previous
//
#include <hip/hip_runtime.h>
#include <hip/hip_bf16.h>

#define DEPTH 25
#define DIM   64
#define HID   100

typedef _Float16 f16x4 __attribute__((ext_vector_type(4)));
typedef float    f32x4 __attribute__((ext_vector_type(4)));
typedef float    f32x2 __attribute__((ext_vector_type(2)));

// ---- Pre-kernel: Levy noise (Chambers-Mallows-Stuck, alpha=1.8, beta=0) ----
// Computed ONCE into d_ws instead of redundantly in all 4096 main blocks.
__global__ __launch_bounds__(64) void levy_noise_kernel(
    const float* __restrict__ u_raw, const float* __restrict__ w_raw,
    float* __restrict__ noise)
{
    const int idx = blockIdx.x * 64 + threadIdx.x;
    if (idx >= DEPTH * DIM) return;
    float u = u_raw[idx];
    float w = w_raw[idx];
    float U  = 3.14159265358979323846f * (u - 0.5f);
    float Wv = -logf(fminf(fmaxf(w, 1e-12f), 1.0f));
    float t1 = sinf(1.8f * U) / powf(cosf(U), 0.5555555555555556f);
    float ratio = cosf(0.8f * U) / fmaxf(Wv, 1e-12f);
    float X = t1 * powf(ratio, -0.4444444444444444f);
    noise[idx] = fminf(fmaxf(0.1f * X, -10.0f), 10.0f);
}

// One block = 256 threads = 4 waves; each wave owns 16 batch rows.
// State kept TRANSPOSED (out^T). v_mfma_f32_16x16x16f16's C/D layout equals
// its B-operand layout, so each step's accumulator maps straight into the
// next step's B fragments (in-lane f32->f16 convert only, no LDS/shuffle).
// dt is folded into W_drift/b_drift: relu(z)*dt = relu(z*dt).
__global__ __launch_bounds__(256) void sdenet_fused(
    const float* __restrict__ x,      const float* __restrict__ noise_g,
    const float* __restrict__ W_down, const float* __restrict__ b_down,
    const float* __restrict__ W_drift,const float* __restrict__ b_drift,
    const float* __restrict__ W1,     const float* __restrict__ b1,
    const float* __restrict__ W2,     const float* __restrict__ b2,
    float* __restrict__ out, int batch)
{
    __shared__ float noise_lds[DEPTH * DIM];

    const int tid = threadIdx.x;
    // copy precomputed noise (L2-resident) into LDS
    {
        const float4* src = (const float4*)noise_g;
        float4* dst = (float4*)noise_lds;
        for (int idx = tid; idx < DEPTH * DIM / 4; idx += 256)
            dst[idx] = src[idx];
    }
    __syncthreads();

    const int wave = tid >> 6;
    const int lane = tid & 63;
    const int r    = lane & 15;        // batch row within wave tile (B col)
    const int g    = lane >> 4;        // k/row group 0..3
    const int row  = blockIdx.x * 64 + wave * 16 + r;
    const float dt = 0.04f;

    // ---- initial: out0^T = W_down^T @ x^T + b_down ----
    f16x4 bfrag[4];
    #pragma unroll
    for (int kt = 0; kt < 4; ++kt) {
        const float4 xv = *(const float4*)(x + row * DIM + kt * 16 + g * 4);
        f16x4 t;
        t[0] = (_Float16)xv.x; t[1] = (_Float16)xv.y;
        t[2] = (_Float16)xv.z; t[3] = (_Float16)xv.w;
        bfrag[kt] = t;
    }

    f32x2 out2[4][2];   // master fp32 state, C/D layout
    #pragma unroll
    for (int Mt = 0; Mt < 4; ++Mt) {
        f32x4 acc = *(const f32x4*)(b_down + Mt * 16 + g * 4);
        #pragma unroll
        for (int kt = 0; kt < 4; ++kt) {
            f16x4 a;
            #pragma unroll
            for (int i = 0; i < 4; ++i)
                a[i] = (_Float16)W_down[(kt * 16 + g * 4 + i) * DIM + Mt * 16 + r];
            acc = __builtin_amdgcn_mfma_f32_16x16x16f16(a, bfrag[kt], acc, 0, 0, 0);
        }
        out2[Mt][0][0] = acc[0]; out2[Mt][0][1] = acc[1];
        out2[Mt][1][0] = acc[2]; out2[Mt][1][1] = acc[3];
    }

    // refresh B fragments from out0
    #pragma unroll
    for (int kt = 0; kt < 4; ++kt) {
        f16x4 t;
        t[0] = (_Float16)out2[kt][0][0]; t[1] = (_Float16)out2[kt][0][1];
        t[2] = (_Float16)out2[kt][1][0]; t[3] = (_Float16)out2[kt][1][1];
        bfrag[kt] = t;
    }

    // ---- head on initial state: logit = relu(out0@W1+b1)@W2 + b2 ----
    float partial = 0.0f;
    #pragma unroll
    for (int Mt = 0; Mt < 7; ++Mt) {          // HID padded 100 -> 112
        f32x4 acc;
        #pragma unroll
        for (int reg = 0; reg < 4; ++reg) {
            int n = Mt * 16 + g * 4 + reg;
            acc[reg] = (n < HID) ? b1[n] : 0.0f;
        }
        const int ncol = Mt * 16 + r;
        #pragma unroll
        for (int kt = 0; kt < 4; ++kt) {
            f16x4 a;
            #pragma unroll
            for (int i = 0; i < 4; ++i) {
                int k = kt * 16 + g * 4 + i;
                float v = (ncol < HID) ? W1[k * HID + ncol] : 0.0f;
                a[i] = (_Float16)v;
            }
            acc = __builtin_amdgcn_mfma_f32_16x16x16f16(a, bfrag[kt], acc, 0, 0, 0);
        }
        #pragma unroll
        for (int reg = 0; reg < 4; ++reg) {
            int n = Mt * 16 + g * 4 + reg;
            if (n < HID) partial += fmaxf(acc[reg], 0.0f) * W2[n];
        }
    }
    partial += __shfl_xor(partial, 16);
    partial += __shfl_xor(partial, 32);
    const float logit = partial + b2[0];
    const float scale = 0.5f * (1.0f / (1.0f + expf(-logit)))
                      * powf(0.04f, 1.0f / 1.8f);
    const f32x2 scale2 = { scale, scale };
    const f32x2 c104   = { 1.04f, 1.04f };
    const f32x2 zero2  = { 0.0f, 0.0f };

    // ---- persistent dt-scaled W_drift^T A-fragments + dt*b_drift ----
    f16x4 aWd[4][4];
    #pragma unroll
    for (int Mt = 0; Mt < 4; ++Mt)
        #pragma unroll
        for (int kt = 0; kt < 4; ++kt) {
            f16x4 a;
            #pragma unroll
            for (int i = 0; i < 4; ++i)
                a[i] = (_Float16)(dt * W_drift[(kt * 16 + g * 4 + i) * DIM + Mt * 16 + r]);
            aWd[Mt][kt] = a;
        }
    f32x4 biasd[4];
    #pragma unroll
    for (int Mt = 0; Mt < 4; ++Mt) {
        f32x4 b = *(const f32x4*)(b_drift + Mt * 16 + g * 4);
        biasd[Mt][0] = b[0] * dt; biasd[Mt][1] = b[1] * dt;
        biasd[Mt][2] = b[2] * dt; biasd[Mt][3] = b[3] * dt;
    }

    // ---- 25 SDE steps, all in registers ----
    for (int t = 0; t < DEPTH; ++t) {
        // issue noise loads before the MFMA chain so ds_read overlaps MFMA
        f32x4 nz[4];
        #pragma unroll
        for (int Mt = 0; Mt < 4; ++Mt)
            nz[Mt] = *(const f32x4*)(noise_lds + t * DIM + Mt * 16 + g * 4);

        f32x4 acc[4];
        #pragma unroll
        for (int Mt = 0; Mt < 4; ++Mt) {
            acc[Mt] = biasd[Mt];
            #pragma unroll
            for (int kt = 0; kt < 4; ++kt)
                acc[Mt] = __builtin_amdgcn_mfma_f32_16x16x16f16(aWd[Mt][kt], bfrag[kt], acc[Mt], 0, 0, 0);
        }
        // out = fma(scale, nz, fma(out, 1.04, relu(acc_dt_scaled)))  [packed f32]
        #pragma unroll
        for (int Mt = 0; Mt < 4; ++Mt) {
            #pragma unroll
            for (int h = 0; h < 2; ++h) {
                f32x2 a2 = { acc[Mt][2 * h], acc[Mt][2 * h + 1] };
                f32x2 n2 = { nz[Mt][2 * h],  nz[Mt][2 * h + 1] };
                f32x2 rel = __builtin_elementwise_max(a2, zero2);
                f32x2 tmp = __builtin_elementwise_fma(out2[Mt][h], c104, rel);
                out2[Mt][h] = __builtin_elementwise_fma(scale2, n2, tmp);
            }
        }
        #pragma unroll
        for (int kt = 0; kt < 4; ++kt) {
            f16x4 tt;
            tt[0] = (_Float16)out2[kt][0][0]; tt[1] = (_Float16)out2[kt][0][1];
            tt[2] = (_Float16)out2[kt][1][0]; tt[3] = (_Float16)out2[kt][1][1];
            bfrag[kt] = tt;
        }
    }

    // ---- final drift (undo dt scaling: relu(z) = relu(dt*z)*25) + stores ----
    const long long out2_off = (long long)batch * DIM;
    #pragma unroll
    for (int Mt = 0; Mt < 4; ++Mt) {
        f32x4 acc = biasd[Mt];
        #pragma unroll
        for (int kt = 0; kt < 4; ++kt)
            acc = __builtin_amdgcn_mfma_f32_16x16x16f16(aWd[Mt][kt], bfrag[kt], acc, 0, 0, 0);
        float o0 = out2[Mt][0][0], o1 = out2[Mt][0][1];
        float o2 = out2[Mt][1][0], o3 = out2[Mt][1][1];
        float4 dv, ov;
        dv.x = fmaf(fmaxf(acc[0], 0.0f), 25.0f, o0);
        dv.y = fmaf(fmaxf(acc[1], 0.0f), 25.0f, o1);
        dv.z = fmaf(fmaxf(acc[2], 0.0f), 25.0f, o2);
        dv.w = fmaf(fmaxf(acc[3], 0.0f), 25.0f, o3);
        ov.x = o0; ov.y = o1; ov.z = o2; ov.w = o3;
        *(float4*)(out + (long long)row * DIM + Mt * 16 + g * 4) = dv;
        *(float4*)(out + out2_off + (long long)row * DIM + Mt * 16 + g * 4) = ov;
    }
}

extern "C" void kernel_launch(void* const* d_in, const int* in_sizes, int n_in,
                              void* d_out, int out_size, void* d_ws, size_t ws_size,
                              hipStream_t stream) {
    const float* x       = (const float*)d_in[0];
    const float* u_raw   = (const float*)d_in[1];
    const float* w_raw   = (const float*)d_in[2];
    const float* W_down  = (const float*)d_in[3];
    const float* b_down  = (const float*)d_in[4];
    const float* W_drift = (const float*)d_in[5];
    const float* b_drift = (const float*)d_in[6];
    const float* W1      = (const float*)d_in[7];
    const float* b1      = (const float*)d_in[8];
    const float* W2      = (const float*)d_in[9];
    const float* b2      = (const float*)d_in[10];
    float* out   = (float*)d_out;
    float* noise = (float*)d_ws;               // 1600 floats scratch

    const int batch = in_sizes[0] / DIM;       // 262144
    const int blocks = batch / 64;

    levy_noise_kernel<<<DEPTH, 64, 0, stream>>>(u_raw, w_raw, noise);
    sdenet_fused<<<blocks, 256, 0, stream>>>(
        x, noise, W_down, b_down, W_drift, b_drift,
        W1, b1, W2, b2, out, batch);
}